// Round 11
// baseline (180.440 us; speedup 1.0000x reference)
//
#include <hip/hip_runtime.h>
#include <hip/hip_bf16.h>

// AttentionBlock B=4, C=128, N=4096.
// gn_wconv (partial stats + w->bf16)
// -> qkv_fused (GN finalize+apply + MFMA QKV; LDS-restaged coalesced stores)
// -> flash_attn (r6 chunk loop + FUSED split-j merge: last-arriver block per
//    (b,iblk) group merges 4 partials + MFMA out-proj + bias + residual)

#define CH 128
#define SEQ 4096
#define EPSV 1e-5f
// 1/sqrt(128) * log2(e): softmax runs in base-2 domain
#define QSCALE (0.08838834764831845f * 1.4426950408889634f)

typedef unsigned short u16;
typedef unsigned int u32;
typedef __attribute__((ext_vector_type(8))) short short8;   // 8 bf16 (4 VGPRs)
typedef __attribute__((ext_vector_type(4))) float floatx4;  // MFMA C/D

__device__ __forceinline__ float bf2f(u16 h) {
    return __uint_as_float(((u32)h) << 16);
}
__device__ __forceinline__ u16 f2bf(float f) {
    u32 u = __float_as_uint(f);
    return (u16)((u + 0x7fffu + ((u >> 16) & 1u)) >> 16);
}
__device__ __forceinline__ u32 pkbf(float a, float b) {   // packed RNE cvt (low=a)
    __hip_bfloat162 h = __float22bfloat162_rn(make_float2(a, b));
    return *(u32*)&h;
}
__device__ __forceinline__ floatx4 mfma16(short8 a, short8 b, floatx4 c) {
    return __builtin_amdgcn_mfma_f32_16x16x32_bf16(a, b, c, 0, 0, 0);
}

// ---------------- Kernel 1: GN partial stats + weight conversion ---------------
// 512 blocks: 0..255 stats (bg,sub), 256..511 weight bf16 convert.
__global__ void gn_wconv(const float* __restrict__ x, float* __restrict__ part,
                         const float* __restrict__ w_qkv, const float* __restrict__ w_out,
                         u16* __restrict__ wq, u16* __restrict__ wo) {
    if (blockIdx.x >= 256) {
        int i = (blockIdx.x - 256) * 256 + threadIdx.x;   // 65536 total
        if (i < 49152) wq[i] = f2bf(w_qkv[i]);
        else           wo[i - 49152] = f2bf(w_out[i - 49152]);
        return;
    }
    int bg = blockIdx.x >> 3, sub = blockIdx.x & 7;
    const float4* xp = (const float4*)(x + (size_t)bg * 65536 + sub * 8192);
    float s = 0.f, sq = 0.f;
    for (int r = 0; r < 8; ++r) {
        float4 v = xp[threadIdx.x + 256 * r];
        s  += v.x + v.y + v.z + v.w;
        sq += v.x*v.x + v.y*v.y + v.z*v.z + v.w*v.w;
    }
    for (int off = 32; off; off >>= 1) {
        s  += __shfl_down(s, off, 64);
        sq += __shfl_down(sq, off, 64);
    }
    __shared__ float ls[8];
    int wave = threadIdx.x >> 6, lane = threadIdx.x & 63;
    if (lane == 0) { ls[wave*2] = s; ls[wave*2+1] = sq; }
    __syncthreads();
    if (threadIdx.x == 0) {
        float ts = 0.f, tq = 0.f;
        for (int w = 0; w < 4; ++w) { ts += ls[w*2]; tq += ls[w*2+1]; }
        part[blockIdx.x * 2]     = ts;
        part[blockIdx.x * 2 + 1] = tq;
    }
}

// ---------------- Kernel 2: fused GN-apply + MFMA QKV projection ---------------
// 512 blocks = (b, 32-pos chunk). hT[32n][136c] in LDS; wave owns 6 o-tiles.
// Epilogue: C tiles -> LDS stage buffers -> fully-coalesced uint4 stores.
__global__ __launch_bounds__(256, 2) void qkv_fused(
        const float* __restrict__ x, const float* __restrict__ gw,
        const float* __restrict__ gb, const float* __restrict__ part,
        const u16* __restrict__ wq, const float* __restrict__ b_qkv,
        u16* __restrict__ qT, u16* __restrict__ kT, u16* __restrict__ v) {
    __shared__ __align__(16) u16 hT[32 * 136];     // input stage
    __shared__ __align__(16) u16 qbuf[32 * 132];   // [n][c] padded
    __shared__ __align__(16) u16 kbuf[32 * 132];
    __shared__ __align__(16) u16 vbuf[128 * 36];   // [c][n] padded
    __shared__ float cw[128], cb[128];
    int bx = blockIdx.x;            // 512
    int nc = bx & 127, b = bx >> 7;
    int n0 = nc * 32;
    int t = threadIdx.x, w = t >> 6, lane = t & 63;
    int quad = lane >> 4, l15 = lane & 15;

    // finalize GN stats -> per-channel scale/bias
    if (t < 128) {
        int g = t >> 4;
        float s = 0.f, sq = 0.f;
        #pragma unroll
        for (int u = 0; u < 8; ++u) {
            s  += part[((b * 8 + g) * 8 + u) * 2];
            sq += part[((b * 8 + g) * 8 + u) * 2 + 1];
        }
        float mean = s / 65536.f;
        float rstd = rsqrtf(sq / 65536.f - mean * mean + EPSV);
        float wgt = gw[t] * rstd;
        cw[t] = wgt;
        cb[t] = gb[t] - mean * wgt;
    }

    // weight fragments: wave w -> o-tiles w*6 .. w*6+5
    short8 wf[6][4];
    float bqk[6];
    #pragma unroll
    for (int j = 0; j < 6; ++j) {
        int orow = (w * 6 + j) * 16 + l15;
        #pragma unroll
        for (int kt = 0; kt < 4; ++kt)
            wf[j][kt] = *(const short8*)(wq + orow * 128 + kt * 32 + quad * 8);
        bqk[j] = b_qkv[orow];
    }
    __syncthreads();

    // stage GN'd x transposed (32 pos x 128 c)
    #pragma unroll
    for (int r = 0; r < 4; ++r) {
        int u = r * 256 + t;
        int c = u >> 3, col = (u & 7) * 4;
        float wgt = cw[c], bs = cb[c];
        float4 xv = *(const float4*)(x + ((size_t)(b * 128 + c)) * SEQ + n0 + col);
        hT[(col + 0) * 136 + c] = f2bf(fmaf(xv.x, wgt, bs));
        hT[(col + 1) * 136 + c] = f2bf(fmaf(xv.y, wgt, bs));
        hT[(col + 2) * 136 + c] = f2bf(fmaf(xv.z, wgt, bs));
        hT[(col + 3) * 136 + c] = f2bf(fmaf(xv.w, wgt, bs));
    }
    __syncthreads();

    #pragma unroll
    for (int nt = 0; nt < 2; ++nt) {
        short8 hf[4];
        #pragma unroll
        for (int kt = 0; kt < 4; ++kt)
            hf[kt] = *(const short8*)(hT + (nt * 16 + l15) * 136 + kt * 32 + quad * 8);
        floatx4 acc[6];
        #pragma unroll
        for (int j = 0; j < 6; ++j) acc[j] = (floatx4)0.f;
        #pragma unroll
        for (int kt = 0; kt < 4; ++kt)
            #pragma unroll
            for (int j = 0; j < 6; ++j) {
                if (w * 6 + j < 16) acc[j] = mfma16(hf[kt], wf[j][kt], acc[j]);
                else                acc[j] = mfma16(wf[j][kt], hf[kt], acc[j]);
            }
        // scatter C tiles into LDS stage buffers
        #pragma unroll
        for (int j = 0; j < 6; ++j) {
            int T = w * 6 + j;
            if (T < 8) {            // q: C[pos][o] -> qbuf[n][c]
                int o = T * 16 + l15;
                #pragma unroll
                for (int r = 0; r < 4; ++r)
                    qbuf[(nt * 16 + quad * 4 + r) * 132 + o] =
                        f2bf((acc[j][r] + bqk[j]) * QSCALE);
            } else if (T < 16) {    // k -> kbuf[n][c]
                int o = (T - 8) * 16 + l15;
                #pragma unroll
                for (int r = 0; r < 4; ++r)
                    kbuf[(nt * 16 + quad * 4 + r) * 132 + o] =
                        f2bf(acc[j][r] + bqk[j]);
            } else {                // v: C[o][pos] -> vbuf[c][n]
                #pragma unroll
                for (int r = 0; r < 4; ++r) {
                    int ov = (T - 16) * 16 + quad * 4 + r;
                    vbuf[ov * 36 + nt * 16 + l15] = f2bf(acc[j][r] + b_qkv[256 + ov]);
                }
            }
        }
    }
    __syncthreads();

    // cooperative coalesced stores
    {   // q,k: [32n][128c] -> contiguous 4096-elem global region each
        u16* qg = qT + ((size_t)b * SEQ + n0) * CH;
        u16* kg = kT + ((size_t)b * SEQ + n0) * CH;
        #pragma unroll
        for (int rep = 0; rep < 2; ++rep) {
            int idx = rep * 256 + t;
            int n = idx >> 4, c8 = (idx & 15) * 8;
            *(uint4*)(qg + n * CH + c8) = *(const uint4*)(qbuf + n * 132 + c8);
            *(uint4*)(kg + n * CH + c8) = *(const uint4*)(kbuf + n * 132 + c8);
        }
        // v: [128c][32n] -> per-c rows of 64 B
        #pragma unroll
        for (int rep = 0; rep < 2; ++rep) {
            int idx = rep * 256 + t;
            int c = idx >> 2, n8 = (idx & 3) * 8;
            *(uint4*)(v + ((size_t)(b * CH + c)) * SEQ + n0 + n8) =
                *(const uint4*)(vbuf + c * 36 + n8);
        }
    }
}

// ---------------- Kernel 3: MFMA flash attention + fused split-j merge ---------
// Chunk loop identical to r6/r10 local optimum (r3 ordering, separate
// kts/vts/ps, 2 blk/CU). After the epilogue each block bumps a per-(b,iblk)
// device-scope counter; the LAST of the 4 j-split blocks acquires and performs
// merge + MFMA out-proj + bias + residual for the whole 128-i group, reusing
// its dead LDS. Saves the merge_out launch + dependency barrier.
__global__ __launch_bounds__(256, 2) void flash_attn(
        const u16* __restrict__ qT, const u16* __restrict__ kT,
        const u16* __restrict__ v, u16* __restrict__ partO,
        float* __restrict__ mbuf, float* __restrict__ lbuf,
        int* __restrict__ cnt, const u16* __restrict__ wo,
        const float* __restrict__ b_out, const float* __restrict__ x,
        float* __restrict__ out) {
    __shared__ __align__(16) char smem[54272];
    u16* kts = (u16*)smem;                 // [64 j][136 c]  17408 B
    u16* vts = (u16*)(smem + 17408);       // [128 c][72 j]  18432 B
    u16* ps  = (u16*)(smem + 35840);       // [128 i][72 j]  18432 B
    u16* qts = (u16*)smem;                 // [128 i][136 c] (init only, 34816 B)
    __shared__ int lastflag;

    int bx = blockIdx.x;                   // 512, r3 ordering
    int js = bx & 3, iblk = (bx >> 2) & 31, b = bx >> 7;
    int t = threadIdx.x, w = t >> 6, lane = t & 63;
    int quad = lane >> 4, l15 = lane & 15;
    int i0 = iblk * 128, j0 = js * 1024;

    // ---- stage Q tile ([n][c]), read B-frags once ----
    {
        const u16* qb = qT + ((size_t)b * SEQ + i0) * CH;
        for (int r = 0; r < 8; ++r) {
            int u = r * 256 + t;
            int i = u >> 4, c16 = u & 15;
            *(uint4*)(qts + i * 136 + c16 * 8) =
                *(const uint4*)(qb + (size_t)i * CH + c16 * 8);
        }
    }
    __syncthreads();
    short8 qf[2][4];
    #pragma unroll
    for (int it = 0; it < 2; ++it)
        #pragma unroll
        for (int kt = 0; kt < 4; ++kt)
            qf[it][kt] = *(const short8*)(qts + (w * 32 + it * 16 + l15) * 136 + kt * 32 + quad * 8);

    float m_run[2] = {-INFINITY, -INFINITY};
    float l_run[2] = {0.f, 0.f};
    floatx4 o[8][2];
    #pragma unroll
    for (int mt = 0; mt < 8; ++mt) { o[mt][0] = (floatx4)0.f; o[mt][1] = (floatx4)0.f; }

    const u16* kTb = kT + ((size_t)b * SEQ + j0) * CH;
    const u16* vb  = v  + (size_t)b * CH * SEQ + j0;

    for (int ch = 0; ch < 16; ++ch) {
        int jb = ch * 64;
        __syncthreads();   // A: prev scores/PV done reading kts/vts; qf read done
        for (int r = 0; r < 4; ++r) {
            int u = r * 256 + t;
            int j = u >> 4, c16 = u & 15;
            *(uint4*)(kts + j * 136 + c16 * 8) =
                *(const uint4*)(kTb + (size_t)(jb + j) * CH + c16 * 8);
        }
        for (int r = 0; r < 4; ++r) {
            int u = r * 256 + t;
            int c = u >> 3, col = u & 7;
            *(uint4*)(vts + c * 72 + col * 8) =
                *(const uint4*)(vb + (size_t)c * SEQ + jb + col * 8);
        }
        __syncthreads();   // B: tiles staged

        // ---- scores S^T: s[jt][it], row=j(quad*4+r), col=i(l15) ----
        floatx4 s[4][2];
        #pragma unroll
        for (int jt = 0; jt < 4; ++jt) { s[jt][0] = (floatx4)0.f; s[jt][1] = (floatx4)0.f; }
        #pragma unroll
        for (int jt = 0; jt < 4; ++jt)
            #pragma unroll
            for (int kt = 0; kt < 4; ++kt) {
                short8 kf = *(const short8*)(kts + (jt * 16 + l15) * 136 + kt * 32 + quad * 8);
                s[jt][0] = mfma16(kf, qf[0][kt], s[jt][0]);
                s[jt][1] = mfma16(kf, qf[1][kt], s[jt][1]);
            }

        // ---- online softmax (base-2), packed P stores to own-wave slab ----
        float al[2];
        #pragma unroll
        for (int it = 0; it < 2; ++it) {
            float mx = s[0][it][0];
            #pragma unroll
            for (int jt = 0; jt < 4; ++jt)
                #pragma unroll
                for (int r = 0; r < 4; ++r) mx = fmaxf(mx, s[jt][it][r]);
            mx = fmaxf(mx, __shfl_xor(mx, 16, 64));
            mx = fmaxf(mx, __shfl_xor(mx, 32, 64));
            float mn = fmaxf(m_run[it], mx);
            al[it] = exp2f(m_run[it] - mn);
            m_run[it] = mn;
            float lsum = 0.f;
            int rowoff = (w * 32 + it * 16 + l15) * 72 + quad * 4;
            #pragma unroll
            for (int jt = 0; jt < 4; ++jt) {
                float p0 = exp2f(s[jt][it][0] - mn);
                float p1 = exp2f(s[jt][it][1] - mn);
                float p2 = exp2f(s[jt][it][2] - mn);
                float p3 = exp2f(s[jt][it][3] - mn);
                lsum += (p0 + p1) + (p2 + p3);
                uint2 pk = make_uint2(pkbf(p0, p1), pkbf(p2, p3));
                *(uint2*)(ps + rowoff + jt * 16) = pk;
            }
            lsum += __shfl_xor(lsum, 16, 64);
            lsum += __shfl_xor(lsum, 32, 64);
            l_run[it] = l_run[it] * al[it] + lsum;
        }
        __builtin_amdgcn_wave_barrier();  // ps writes (own slab) before reads

        // ---- PV: O^T[c][i] += V[c][j] * P[i][j]^T ----
        float a0 = al[0], a1 = al[1];
        #pragma unroll
        for (int mt = 0; mt < 8; ++mt) { o[mt][0] *= a0; o[mt][1] *= a1; }
        #pragma unroll
        for (int kt = 0; kt < 2; ++kt) {
            short8 pf0 = *(const short8*)(ps + (w * 32 + l15) * 72 + kt * 32 + quad * 8);
            short8 pf1 = *(const short8*)(ps + (w * 32 + 16 + l15) * 72 + kt * 32 + quad * 8);
            #pragma unroll
            for (int mt = 0; mt < 8; ++mt) {
                short8 vf = *(const short8*)(vts + (mt * 16 + l15) * 72 + kt * 32 + quad * 8);
                o[mt][0] = mfma16(vf, pf0, o[mt][0]);
                o[mt][1] = mfma16(vf, pf1, o[mt][1]);
            }
        }
    }

    // ---- epilogue: partial O (bf16) in [i][c] layout, packed stores ----
    int bi = b * 32 + iblk;
    u16* pb = partO + ((size_t)(js * 128 + bi)) * 16384;   // [128 i][128 c]
    #pragma unroll
    for (int it = 0; it < 2; ++it) {
        int i = w * 32 + it * 16 + l15;
        #pragma unroll
        for (int mt = 0; mt < 8; ++mt) {
            uint2 pk = make_uint2(pkbf(o[mt][it][0], o[mt][it][1]),
                                  pkbf(o[mt][it][2], o[mt][it][3]));
            *(uint2*)(pb + i * 128 + mt * 16 + quad * 4) = pk;
        }
    }
    if (lane < 16) {   // stats are quad-replicated after butterfly
        float* mb = mbuf + ((size_t)(js * 128 + bi)) * 128;
        float* lb = lbuf + ((size_t)(js * 128 + bi)) * 128;
        #pragma unroll
        for (int it = 0; it < 2; ++it) {
            int i = w * 32 + it * 16 + l15;
            mb[i] = m_run[it];
            lb[i] = l_run[it];
        }
    }

    // ---- split-j rendezvous: last arriver merges ----
    __syncthreads();               // all threads' partO/m/l stores drained (vmcnt)
    if (t == 0) {
        __threadfence();           // release: visible device-wide (cross-XCD)
        int old = atomicAdd(&cnt[bi], 1);
        lastflag = (old == 3);
        if (lastflag) __threadfence();  // acquire before reading peers' data
    }
    __syncthreads();
    if (!lastflag) return;

    // ---- merge 4 partials + MFMA out-proj + bias + residual (128 i) ----
    u16*  h2T = (u16*)smem;                 // [32 i][136 c]  8704 B (reuse)
    float* fac = (float*)(smem + 8704);     // [4][128]       2048 B

    short8 wf[2][4];
    #pragma unroll
    for (int j = 0; j < 2; ++j)
        #pragma unroll
        for (int kt = 0; kt < 4; ++kt)
            wf[j][kt] = *(const short8*)(wo + ((w * 2 + j) * 16 + l15) * 128 + kt * 32 + quad * 8);

    if (t < 128) {
        float mv[4], lv[4];
        #pragma unroll
        for (int s = 0; s < 4; ++s) {
            mv[s] = mbuf[((size_t)(s * 128 + bi)) * 128 + t];
            lv[s] = lbuf[((size_t)(s * 128 + bi)) * 128 + t];
        }
        float M = mv[0];
        #pragma unroll
        for (int s = 1; s < 4; ++s) M = fmaxf(M, mv[s]);
        float wsum = 0.f, wss[4];
        #pragma unroll
        for (int s = 0; s < 4; ++s) { wss[s] = exp2f(mv[s] - M); wsum += wss[s] * lv[s]; }
        float inv = 1.f / wsum;
        #pragma unroll
        for (int s = 0; s < 4; ++s) fac[s * 128 + t] = wss[s] * inv;
    }
    __syncthreads();

    for (int qtr = 0; qtr < 4; ++qtr) {
        // merge: thread -> (il = t>>3 in 0..31, oct = t&7 -> 16-c strip)
        {
            int il = t >> 3, oct = t & 7;
            int i = qtr * 32 + il;
            float accv[16];
            #pragma unroll
            for (int e = 0; e < 16; ++e) accv[e] = 0.f;
            for (int s = 0; s < 4; ++s) {
                const u16* pr = partO + ((size_t)(s * 128 + bi)) * 16384
                                + i * 128 + oct * 16;
                u16 a[16];
                *(uint4*)(a)     = *(const uint4*)(pr);
                *(uint4*)(a + 8) = *(const uint4*)(pr + 8);
                float fs = fac[s * 128 + i];
                #pragma unroll
                for (int e = 0; e < 16; ++e) accv[e] = fmaf(bf2f(a[e]), fs, accv[e]);
            }
            uint4 lo = make_uint4(pkbf(accv[0],  accv[1]),  pkbf(accv[2],  accv[3]),
                                  pkbf(accv[4],  accv[5]),  pkbf(accv[6],  accv[7]));
            uint4 hi = make_uint4(pkbf(accv[8],  accv[9]),  pkbf(accv[10], accv[11]),
                                  pkbf(accv[12], accv[13]), pkbf(accv[14], accv[15]));
            *(uint4*)(h2T + il * 136 + oct * 16)     = lo;
            *(uint4*)(h2T + il * 136 + oct * 16 + 8) = hi;
        }
        __syncthreads();

        floatx4 acc[2][2];
        #pragma unroll
        for (int j = 0; j < 2; ++j) { acc[j][0] = (floatx4)0.f; acc[j][1] = (floatx4)0.f; }
        #pragma unroll
        for (int nt = 0; nt < 2; ++nt)
            #pragma unroll
            for (int kt = 0; kt < 4; ++kt) {
                short8 hf = *(const short8*)(h2T + (nt * 16 + l15) * 136 + kt * 32 + quad * 8);
                acc[0][nt] = mfma16(wf[0][kt], hf, acc[0][nt]);
                acc[1][nt] = mfma16(wf[1][kt], hf, acc[1][nt]);
            }

        int n_base = iblk * 128 + qtr * 32;
        #pragma unroll
        for (int j = 0; j < 2; ++j)
            #pragma unroll
            for (int r = 0; r < 4; ++r) {
                int oo = w * 32 + j * 16 + quad * 4 + r;
                float bo = b_out[oo];
                #pragma unroll
                for (int nt = 0; nt < 2; ++nt) {
                    int n = n_base + nt * 16 + l15;
                    size_t idx = ((size_t)(b * 128 + oo)) * SEQ + n;
                    out[idx] = acc[j][nt][r] + bo + x[idx];
                }
            }
        __syncthreads();   // h2T reused next qtr
    }
}

// ---------------- launch -------------------------------------------------------
extern "C" void kernel_launch(void* const* d_in, const int* in_sizes, int n_in,
                              void* d_out, int out_size, void* d_ws, size_t ws_size,
                              hipStream_t stream) {
    const float* x     = (const float*)d_in[0];
    const float* gn_w  = (const float*)d_in[1];
    const float* gn_b  = (const float*)d_in[2];
    const float* w_qkv = (const float*)d_in[3];
    const float* b_qkv = (const float*)d_in[4];
    const float* w_out = (const float*)d_in[5];
    const float* b_out = (const float*)d_in[6];
    float* out = (float*)d_out;

    char* ws = (char*)d_ws;
    float* part = (float*)ws;                  //   2 KB @ 0
    int*  cnt = (int*)(ws + 2048);             // 512 B group counters
    u16*  wq  = (u16*)(ws + 4096);             //  96 KB
    u16*  wo  = (u16*)(ws + 102400);           //  32 KB
    u16*  qT  = (u16*)(ws + 135168);           //   4 MB [b][n][c]
    u16*  kT  = (u16*)(ws + 4329472);          //   4 MB [b][n][c]
    u16*  v   = (u16*)(ws + 8523776);          //   4 MB [b][c][n]
    u16*  pO  = (u16*)(ws + 12718080);         //  16 MB partials [js][bi][i][c]
    float* mb = (float*)(ws + 29495296);       // 256 KB
    float* lb = (float*)(ws + 29757440);       // 256 KB
    // total ~30 MB

    hipMemsetAsync(cnt, 0, 512, stream);       // zero rendezvous counters
    gn_wconv<<<512, 256, 0, stream>>>(x, part, w_qkv, w_out, wq, wo);
    qkv_fused<<<512, 256, 0, stream>>>(x, gn_w, gn_b, part, wq, b_qkv, qT, kT, v);
    flash_attn<<<512, 256, 0, stream>>>(qT, kT, v, pO, mb, lb, cnt, wo, b_out, x, out);
}

// Round 12
// 146.706 us; speedup vs baseline: 1.2299x; 1.2299x over previous
//
#include <hip/hip_runtime.h>
#include <hip/hip_bf16.h>

// AttentionBlock B=4, C=128, N=4096.
// gn_wconv (partial stats + w->bf16)
// -> qkv_fused (GN finalize+apply + MFMA QKV; LDS-restaged coalesced stores)
// -> flash_attn (r10 chunk loop; FIXED-MAX softmax M=24: no running max,
//                no alpha rescale, deferred l reduction)
// -> merge_out (sum 4 partials * 1/l + MFMA out-proj + bias + residual)

#define CH 128
#define SEQ 4096
#define EPSV 1e-5f
// 1/sqrt(128) * log2(e): softmax runs in base-2 domain
#define QSCALE (0.08838834764831845f * 1.4426950408889634f)
// fixed softmax shift: base-2 logits here are bounded |s2| <~ 15; exp2 only
// overflows at s2-M > 127 -> enormous margin. Same M for all j-splits makes
// merge factors collapse to 1/sum(l).
#define SMAX 24.0f

typedef unsigned short u16;
typedef unsigned int u32;
typedef __attribute__((ext_vector_type(8))) short short8;   // 8 bf16 (4 VGPRs)
typedef __attribute__((ext_vector_type(4))) float floatx4;  // MFMA C/D

__device__ __forceinline__ float bf2f(u16 h) {
    return __uint_as_float(((u32)h) << 16);
}
__device__ __forceinline__ u16 f2bf(float f) {
    u32 u = __float_as_uint(f);
    return (u16)((u + 0x7fffu + ((u >> 16) & 1u)) >> 16);
}
__device__ __forceinline__ u32 pkbf(float a, float b) {   // packed RNE cvt (low=a)
    __hip_bfloat162 h = __float22bfloat162_rn(make_float2(a, b));
    return *(u32*)&h;
}
__device__ __forceinline__ floatx4 mfma16(short8 a, short8 b, floatx4 c) {
    return __builtin_amdgcn_mfma_f32_16x16x32_bf16(a, b, c, 0, 0, 0);
}

// ---------------- Kernel 1: GN partial stats + weight conversion ---------------
// 512 blocks: 0..255 stats (bg,sub), 256..511 weight bf16 convert.
__global__ void gn_wconv(const float* __restrict__ x, float* __restrict__ part,
                         const float* __restrict__ w_qkv, const float* __restrict__ w_out,
                         u16* __restrict__ wq, u16* __restrict__ wo) {
    if (blockIdx.x >= 256) {
        int i = (blockIdx.x - 256) * 256 + threadIdx.x;   // 65536 total
        if (i < 49152) wq[i] = f2bf(w_qkv[i]);
        else           wo[i - 49152] = f2bf(w_out[i - 49152]);
        return;
    }
    int bg = blockIdx.x >> 3, sub = blockIdx.x & 7;
    const float4* xp = (const float4*)(x + (size_t)bg * 65536 + sub * 8192);
    float s = 0.f, sq = 0.f;
    for (int r = 0; r < 8; ++r) {
        float4 v = xp[threadIdx.x + 256 * r];
        s  += v.x + v.y + v.z + v.w;
        sq += v.x*v.x + v.y*v.y + v.z*v.z + v.w*v.w;
    }
    for (int off = 32; off; off >>= 1) {
        s  += __shfl_down(s, off, 64);
        sq += __shfl_down(sq, off, 64);
    }
    __shared__ float ls[8];
    int wave = threadIdx.x >> 6, lane = threadIdx.x & 63;
    if (lane == 0) { ls[wave*2] = s; ls[wave*2+1] = sq; }
    __syncthreads();
    if (threadIdx.x == 0) {
        float ts = 0.f, tq = 0.f;
        for (int w = 0; w < 4; ++w) { ts += ls[w*2]; tq += ls[w*2+1]; }
        part[blockIdx.x * 2]     = ts;
        part[blockIdx.x * 2 + 1] = tq;
    }
}

// ---------------- Kernel 2: fused GN-apply + MFMA QKV projection ---------------
// 512 blocks = (b, 32-pos chunk). hT[32n][136c] in LDS; wave owns 6 o-tiles.
// Epilogue: C tiles -> LDS stage buffers -> fully-coalesced uint4 stores.
__global__ __launch_bounds__(256, 2) void qkv_fused(
        const float* __restrict__ x, const float* __restrict__ gw,
        const float* __restrict__ gb, const float* __restrict__ part,
        const u16* __restrict__ wq, const float* __restrict__ b_qkv,
        u16* __restrict__ qT, u16* __restrict__ kT, u16* __restrict__ v) {
    __shared__ __align__(16) u16 hT[32 * 136];     // input stage
    __shared__ __align__(16) u16 qbuf[32 * 132];   // [n][c] padded
    __shared__ __align__(16) u16 kbuf[32 * 132];
    __shared__ __align__(16) u16 vbuf[128 * 36];   // [c][n] padded
    __shared__ float cw[128], cb[128];
    int bx = blockIdx.x;            // 512
    int nc = bx & 127, b = bx >> 7;
    int n0 = nc * 32;
    int t = threadIdx.x, w = t >> 6, lane = t & 63;
    int quad = lane >> 4, l15 = lane & 15;

    // finalize GN stats -> per-channel scale/bias
    if (t < 128) {
        int g = t >> 4;
        float s = 0.f, sq = 0.f;
        #pragma unroll
        for (int u = 0; u < 8; ++u) {
            s  += part[((b * 8 + g) * 8 + u) * 2];
            sq += part[((b * 8 + g) * 8 + u) * 2 + 1];
        }
        float mean = s / 65536.f;
        float rstd = rsqrtf(sq / 65536.f - mean * mean + EPSV);
        float wgt = gw[t] * rstd;
        cw[t] = wgt;
        cb[t] = gb[t] - mean * wgt;
    }

    // weight fragments: wave w -> o-tiles w*6 .. w*6+5
    short8 wf[6][4];
    float bqk[6];
    #pragma unroll
    for (int j = 0; j < 6; ++j) {
        int orow = (w * 6 + j) * 16 + l15;
        #pragma unroll
        for (int kt = 0; kt < 4; ++kt)
            wf[j][kt] = *(const short8*)(wq + orow * 128 + kt * 32 + quad * 8);
        bqk[j] = b_qkv[orow];
    }
    __syncthreads();

    // stage GN'd x transposed (32 pos x 128 c)
    #pragma unroll
    for (int r = 0; r < 4; ++r) {
        int u = r * 256 + t;
        int c = u >> 3, col = (u & 7) * 4;
        float wgt = cw[c], bs = cb[c];
        float4 xv = *(const float4*)(x + ((size_t)(b * 128 + c)) * SEQ + n0 + col);
        hT[(col + 0) * 136 + c] = f2bf(fmaf(xv.x, wgt, bs));
        hT[(col + 1) * 136 + c] = f2bf(fmaf(xv.y, wgt, bs));
        hT[(col + 2) * 136 + c] = f2bf(fmaf(xv.z, wgt, bs));
        hT[(col + 3) * 136 + c] = f2bf(fmaf(xv.w, wgt, bs));
    }
    __syncthreads();

    #pragma unroll
    for (int nt = 0; nt < 2; ++nt) {
        short8 hf[4];
        #pragma unroll
        for (int kt = 0; kt < 4; ++kt)
            hf[kt] = *(const short8*)(hT + (nt * 16 + l15) * 136 + kt * 32 + quad * 8);
        floatx4 acc[6];
        #pragma unroll
        for (int j = 0; j < 6; ++j) acc[j] = (floatx4)0.f;
        #pragma unroll
        for (int kt = 0; kt < 4; ++kt)
            #pragma unroll
            for (int j = 0; j < 6; ++j) {
                if (w * 6 + j < 16) acc[j] = mfma16(hf[kt], wf[j][kt], acc[j]);
                else                acc[j] = mfma16(wf[j][kt], hf[kt], acc[j]);
            }
        // scatter C tiles into LDS stage buffers
        #pragma unroll
        for (int j = 0; j < 6; ++j) {
            int T = w * 6 + j;
            if (T < 8) {            // q: C[pos][o] -> qbuf[n][c]
                int o = T * 16 + l15;
                #pragma unroll
                for (int r = 0; r < 4; ++r)
                    qbuf[(nt * 16 + quad * 4 + r) * 132 + o] =
                        f2bf((acc[j][r] + bqk[j]) * QSCALE);
            } else if (T < 16) {    // k -> kbuf[n][c]
                int o = (T - 8) * 16 + l15;
                #pragma unroll
                for (int r = 0; r < 4; ++r)
                    kbuf[(nt * 16 + quad * 4 + r) * 132 + o] =
                        f2bf(acc[j][r] + bqk[j]);
            } else {                // v: C[o][pos] -> vbuf[c][n]
                #pragma unroll
                for (int r = 0; r < 4; ++r) {
                    int ov = (T - 16) * 16 + quad * 4 + r;
                    vbuf[ov * 36 + nt * 16 + l15] = f2bf(acc[j][r] + b_qkv[256 + ov]);
                }
            }
        }
    }
    __syncthreads();

    // cooperative coalesced stores
    {   // q,k: [32n][128c] -> contiguous 4096-elem global region each
        u16* qg = qT + ((size_t)b * SEQ + n0) * CH;
        u16* kg = kT + ((size_t)b * SEQ + n0) * CH;
        #pragma unroll
        for (int rep = 0; rep < 2; ++rep) {
            int idx = rep * 256 + t;
            int n = idx >> 4, c8 = (idx & 15) * 8;
            *(uint4*)(qg + n * CH + c8) = *(const uint4*)(qbuf + n * 132 + c8);
            *(uint4*)(kg + n * CH + c8) = *(const uint4*)(kbuf + n * 132 + c8);
        }
        // v: [128c][32n] -> per-c rows of 64 B
        #pragma unroll
        for (int rep = 0; rep < 2; ++rep) {
            int idx = rep * 256 + t;
            int c = idx >> 2, n8 = (idx & 3) * 8;
            *(uint4*)(v + ((size_t)(b * CH + c)) * SEQ + n0 + n8) =
                *(const uint4*)(vbuf + c * 36 + n8);
        }
    }
}

// ---------------- Kernel 3: MFMA flash attention (fixed-max softmax) -----------
// r3 block ordering (js fastest -> L2/XCD locality) + separate kts/vts/ps
// (54.2 KB, 2 blk/CU — measured local optimum). S^T scores (A=K, B=Q).
// Softmax uses FIXED shift M=SMAX: no running max, no alpha rescale of O,
// per-lane l partials reduced once in the epilogue.
// 512 blocks = (b, iblk of 128 i, js of 4); 16 chunks of BN=64 per split.
__global__ __launch_bounds__(256, 2) void flash_attn(
        const u16* __restrict__ qT, const u16* __restrict__ kT,
        const u16* __restrict__ v, u16* __restrict__ partO,
        float* __restrict__ lbuf) {
    __shared__ __align__(16) char smem[54272];
    u16* kts = (u16*)smem;                 // [64 j][136 c]  17408 B
    u16* vts = (u16*)(smem + 17408);       // [128 c][72 j]  18432 B
    u16* ps  = (u16*)(smem + 35840);       // [128 i][72 j]  18432 B
    u16* qts = (u16*)smem;                 // [128 i][136 c] (init only, 34816 B)

    int bx = blockIdx.x;                   // 512, r3 ordering
    int js = bx & 3, iblk = (bx >> 2) & 31, b = bx >> 7;
    int t = threadIdx.x, w = t >> 6, lane = t & 63;
    int quad = lane >> 4, l15 = lane & 15;
    int i0 = iblk * 128, j0 = js * 1024;

    // ---- stage Q tile ([n][c]), read B-frags once ----
    {
        const u16* qb = qT + ((size_t)b * SEQ + i0) * CH;
        for (int r = 0; r < 8; ++r) {
            int u = r * 256 + t;
            int i = u >> 4, c16 = u & 15;
            *(uint4*)(qts + i * 136 + c16 * 8) =
                *(const uint4*)(qb + (size_t)i * CH + c16 * 8);
        }
    }
    __syncthreads();
    short8 qf[2][4];
    #pragma unroll
    for (int it = 0; it < 2; ++it)
        #pragma unroll
        for (int kt = 0; kt < 4; ++kt)
            qf[it][kt] = *(const short8*)(qts + (w * 32 + it * 16 + l15) * 136 + kt * 32 + quad * 8);

    float l_part[2] = {0.f, 0.f};   // per-lane partial sums (reduced at end)
    floatx4 o[8][2];
    #pragma unroll
    for (int mt = 0; mt < 8; ++mt) { o[mt][0] = (floatx4)0.f; o[mt][1] = (floatx4)0.f; }

    const u16* kTb = kT + ((size_t)b * SEQ + j0) * CH;
    const u16* vb  = v  + (size_t)b * CH * SEQ + j0;

    for (int ch = 0; ch < 16; ++ch) {
        int jb = ch * 64;
        __syncthreads();   // A: prev scores/PV done reading kts/vts; qf read done
        for (int r = 0; r < 4; ++r) {
            int u = r * 256 + t;
            int j = u >> 4, c16 = u & 15;
            *(uint4*)(kts + j * 136 + c16 * 8) =
                *(const uint4*)(kTb + (size_t)(jb + j) * CH + c16 * 8);
        }
        for (int r = 0; r < 4; ++r) {
            int u = r * 256 + t;
            int c = u >> 3, col = u & 7;
            *(uint4*)(vts + c * 72 + col * 8) =
                *(const uint4*)(vb + (size_t)c * SEQ + jb + col * 8);
        }
        __syncthreads();   // B: tiles staged

        // ---- scores S^T: s[jt][it], row=j(quad*4+r), col=i(l15) ----
        floatx4 s[4][2];
        #pragma unroll
        for (int jt = 0; jt < 4; ++jt) { s[jt][0] = (floatx4)0.f; s[jt][1] = (floatx4)0.f; }
        #pragma unroll
        for (int jt = 0; jt < 4; ++jt)
            #pragma unroll
            for (int kt = 0; kt < 4; ++kt) {
                short8 kf = *(const short8*)(kts + (jt * 16 + l15) * 136 + kt * 32 + quad * 8);
                s[jt][0] = mfma16(kf, qf[0][kt], s[jt][0]);
                s[jt][1] = mfma16(kf, qf[1][kt], s[jt][1]);
            }

        // ---- softmax numerator (base-2, fixed shift), packed P stores ----
        #pragma unroll
        for (int it = 0; it < 2; ++it) {
            float lsum = 0.f;
            int rowoff = (w * 32 + it * 16 + l15) * 72 + quad * 4;
            #pragma unroll
            for (int jt = 0; jt < 4; ++jt) {
                float p0 = exp2f(s[jt][it][0] - SMAX);
                float p1 = exp2f(s[jt][it][1] - SMAX);
                float p2 = exp2f(s[jt][it][2] - SMAX);
                float p3 = exp2f(s[jt][it][3] - SMAX);
                lsum += (p0 + p1) + (p2 + p3);
                uint2 pk = make_uint2(pkbf(p0, p1), pkbf(p2, p3));
                *(uint2*)(ps + rowoff + jt * 16) = pk;
            }
            l_part[it] += lsum;
        }
        __builtin_amdgcn_wave_barrier();  // ps writes (own slab) before reads

        // ---- PV: O^T[c][i] += V[c][j] * P[i][j]^T (no rescale needed) ----
        #pragma unroll
        for (int kt = 0; kt < 2; ++kt) {
            short8 pf0 = *(const short8*)(ps + (w * 32 + l15) * 72 + kt * 32 + quad * 8);
            short8 pf1 = *(const short8*)(ps + (w * 32 + 16 + l15) * 72 + kt * 32 + quad * 8);
            #pragma unroll
            for (int mt = 0; mt < 8; ++mt) {
                short8 vf = *(const short8*)(vts + (mt * 16 + l15) * 72 + kt * 32 + quad * 8);
                o[mt][0] = mfma16(vf, pf0, o[mt][0]);
                o[mt][1] = mfma16(vf, pf1, o[mt][1]);
            }
        }
    }

    // ---- epilogue: partial O (bf16) in [i][c] layout, packed stores ----
    // C layout: i = w*32 + it*16 + l15 (col), c = mt*16 + quad*4 + r (row).
    int bi = b * 32 + iblk;
    u16* pb = partO + ((size_t)(js * 128 + bi)) * 16384;   // [128 i][128 c]
    #pragma unroll
    for (int it = 0; it < 2; ++it) {
        int i = w * 32 + it * 16 + l15;
        #pragma unroll
        for (int mt = 0; mt < 8; ++mt) {
            uint2 pk = make_uint2(pkbf(o[mt][it][0], o[mt][it][1]),
                                  pkbf(o[mt][it][2], o[mt][it][3]));
            *(uint2*)(pb + i * 128 + mt * 16 + quad * 4) = pk;
        }
    }
    // reduce l partials across the 4 quads (columns share l15), then store
    float* lb = lbuf + ((size_t)(js * 128 + bi)) * 128;
    #pragma unroll
    for (int it = 0; it < 2; ++it) {
        float l = l_part[it];
        l += __shfl_xor(l, 16, 64);
        l += __shfl_xor(l, 32, 64);
        if (lane < 16) lb[w * 32 + it * 16 + l15] = l;
    }
}

// ---------------- Kernel 4: merge 4 partials + MFMA out-proj + residual --------
// 512 blocks = (b, iblk, quarter of 32 pos). Fixed softmax shift -> merge is
// just (sum of partials) * 1/(sum of l). partO [i][c]: coalesced row reads.
__global__ __launch_bounds__(256, 2) void merge_out(
        const u16* __restrict__ partO, const float* __restrict__ lbuf,
        const u16* __restrict__ wo, const float* __restrict__ b_out,
        const float* __restrict__ x, float* __restrict__ out) {
    __shared__ __align__(16) u16 h2T[32 * 136];
    __shared__ float fac[32];
    int bx = blockIdx.x;           // 512
    int qtr = bx & 3, iblk = (bx >> 2) & 31, b = bx >> 7;
    int bi = b * 32 + iblk;
    int i_base = qtr * 32;
    int t = threadIdx.x, w = t >> 6, lane = t & 63;
    int quad = lane >> 4, l15 = lane & 15;

    short8 wf[2][4];
    #pragma unroll
    for (int j = 0; j < 2; ++j)
        #pragma unroll
        for (int kt = 0; kt < 4; ++kt)
            wf[j][kt] = *(const short8*)(wo + ((w * 2 + j) * 16 + l15) * 128 + kt * 32 + quad * 8);

    if (t < 32) {
        int i = i_base + t;
        float lv = 0.f;
        #pragma unroll
        for (int s = 0; s < 4; ++s)
            lv += lbuf[((size_t)(s * 128 + bi)) * 128 + i];
        fac[t] = 1.f / lv;
    }
    __syncthreads();

    // merge: thread -> (il = t>>3 in 0..31, oct = t&7 -> 16-c strip)
    {
        int il = t >> 3, oct = t & 7;
        int i = i_base + il;
        float accv[16];
        #pragma unroll
        for (int e = 0; e < 16; ++e) accv[e] = 0.f;
        for (int s = 0; s < 4; ++s) {
            const u16* pb = partO + ((size_t)(s * 128 + bi)) * 16384
                            + i * 128 + oct * 16;
            u16 a[16];
            *(uint4*)(a)     = *(const uint4*)(pb);
            *(uint4*)(a + 8) = *(const uint4*)(pb + 8);
            #pragma unroll
            for (int e = 0; e < 16; ++e) accv[e] += bf2f(a[e]);
        }
        float fs = fac[il];
        #pragma unroll
        for (int e = 0; e < 16; ++e) accv[e] *= fs;
        uint4 lo = make_uint4(pkbf(accv[0],  accv[1]),  pkbf(accv[2],  accv[3]),
                              pkbf(accv[4],  accv[5]),  pkbf(accv[6],  accv[7]));
        uint4 hi = make_uint4(pkbf(accv[8],  accv[9]),  pkbf(accv[10], accv[11]),
                              pkbf(accv[12], accv[13]), pkbf(accv[14], accv[15]));
        *(uint4*)(h2T + il * 136 + oct * 16)     = lo;
        *(uint4*)(h2T + il * 136 + oct * 16 + 8) = hi;
    }
    __syncthreads();

    floatx4 acc[2][2];
    #pragma unroll
    for (int j = 0; j < 2; ++j) { acc[j][0] = (floatx4)0.f; acc[j][1] = (floatx4)0.f; }
    #pragma unroll
    for (int nt = 0; nt < 2; ++nt)
        #pragma unroll
        for (int kt = 0; kt < 4; ++kt) {
            short8 hf = *(const short8*)(h2T + (nt * 16 + l15) * 136 + kt * 32 + quad * 8);
            acc[0][nt] = mfma16(wf[0][kt], hf, acc[0][nt]);
            acc[1][nt] = mfma16(wf[1][kt], hf, acc[1][nt]);
        }

    int n_base = iblk * 128 + i_base;
    #pragma unroll
    for (int j = 0; j < 2; ++j)
        #pragma unroll
        for (int r = 0; r < 4; ++r) {
            int o = w * 32 + j * 16 + quad * 4 + r;
            float bo = b_out[o];
            #pragma unroll
            for (int nt = 0; nt < 2; ++nt) {
                int n = n_base + nt * 16 + l15;
                size_t idx = ((size_t)(b * 128 + o)) * SEQ + n;
                out[idx] = acc[j][nt][r] + bo + x[idx];
            }
        }
}

// ---------------- launch -------------------------------------------------------
extern "C" void kernel_launch(void* const* d_in, const int* in_sizes, int n_in,
                              void* d_out, int out_size, void* d_ws, size_t ws_size,
                              hipStream_t stream) {
    const float* x     = (const float*)d_in[0];
    const float* gn_w  = (const float*)d_in[1];
    const float* gn_b  = (const float*)d_in[2];
    const float* w_qkv = (const float*)d_in[3];
    const float* b_qkv = (const float*)d_in[4];
    const float* w_out = (const float*)d_in[5];
    const float* b_out = (const float*)d_in[6];
    float* out = (float*)d_out;

    char* ws = (char*)d_ws;
    float* part = (float*)ws;                  //   2 KB @ 0
    u16*  wq  = (u16*)(ws + 4096);             //  96 KB
    u16*  wo  = (u16*)(ws + 102400);           //  32 KB
    u16*  qT  = (u16*)(ws + 135168);           //   4 MB [b][n][c]
    u16*  kT  = (u16*)(ws + 4329472);          //   4 MB [b][n][c]
    u16*  v   = (u16*)(ws + 8523776);          //   4 MB [b][c][n]
    u16*  pO  = (u16*)(ws + 12718080);         //  16 MB partials [js][bi][i][c]
    float* lb = (float*)(ws + 29495296);       // 256 KB
    // total ~29.8 MB

    gn_wconv<<<512, 256, 0, stream>>>(x, part, w_qkv, w_out, wq, wo);
    qkv_fused<<<512, 256, 0, stream>>>(x, gn_w, gn_b, part, wq, b_qkv, qT, kT, v);
    flash_attn<<<512, 256, 0, stream>>>(qT, kT, v, pO, lb);
    merge_out<<<512, 256, 0, stream>>>(pO, lb, wo, b_out, x, out);
}